// Round 13
// baseline (184.677 us; speedup 1.0000x reference)
//
#include <hip/hip_runtime.h>
#include <hip/hip_bf16.h>

#define BB 2
#define SS 2048
#define DD 1024
#define HH 16
#define HD 64

typedef __attribute__((ext_vector_type(8))) short bf16x8;
typedef __attribute__((ext_vector_type(4))) float f32x4;

// round-to-nearest-even f32 -> bf16 (inputs finite)
__device__ __forceinline__ unsigned short f2bf(float f) {
  unsigned int u = __float_as_uint(f);
  return (unsigned short)((u + 0x7FFFu + ((u >> 16) & 1u)) >> 16);
}

// 2^x via hardware v_exp_f32
__device__ __forceinline__ float fast_exp2(float x) {
#if __has_builtin(__builtin_amdgcn_exp2f)
  return __builtin_amdgcn_exp2f(x);
#else
  return __expf(x * 0.6931471805599453f);
#endif
}

__device__ __forceinline__ void async_copy16(const unsigned short* gp, unsigned short* lp) {
  __builtin_amdgcn_global_load_lds(
      (const __attribute__((address_space(1))) unsigned int*)gp,
      (__attribute__((address_space(3))) unsigned int*)lp, 16, 0, 0);
}

// gfx950 cross-lane register swaps (VALU, not DS pipe).
__device__ __forceinline__ void pl32_swap(unsigned& a, unsigned& b) {
#if __has_builtin(__builtin_amdgcn_permlane32_swap)
  auto r = __builtin_amdgcn_permlane32_swap(a, b, false, false);
  a = r[0];
  b = r[1];
#else
  asm volatile("v_permlane32_swap_b32 %0, %1" : "+v"(a), "+v"(b));
#endif
}
__device__ __forceinline__ void pl16_swap(unsigned& a, unsigned& b) {
#if __has_builtin(__builtin_amdgcn_permlane16_swap)
  auto r = __builtin_amdgcn_permlane16_swap(a, b, false, false);
  a = r[0];
  b = r[1];
#else
  asm volatile("v_permlane16_swap_b32 %0, %1" : "+v"(a), "+v"(b));
#endif
}

// ---------------------------------------------------------------------------
// Fused prep: blocks [0,4096) convert x -> bf16; blocks [4096,8192) transpose
// one of the 4 weight matrices (1024 32x32 tiles each) to bf16 [N][K].
// ---------------------------------------------------------------------------
__global__ __launch_bounds__(256) void prep_kernel(
    const float* __restrict__ x, unsigned short* __restrict__ xb,
    const float* __restrict__ W0, unsigned short* __restrict__ T0,
    const float* __restrict__ W1, unsigned short* __restrict__ T1,
    const float* __restrict__ W2, unsigned short* __restrict__ T2,
    const float* __restrict__ W3, unsigned short* __restrict__ T3) {
  const int blk = blockIdx.x;
  const int t = threadIdx.x;
  if (blk < 4096) {
    int i = blk * 1024 + t * 4;
    float4 v = *(const float4*)(x + i);
    ushort4 u;
    u.x = f2bf(v.x); u.y = f2bf(v.y); u.z = f2bf(v.z); u.w = f2bf(v.w);
    *(ushort4*)(xb + i) = u;
    return;
  }
  const int j = blk - 4096;
  const int jw = j >> 10;          // which weight
  const int tb = j & 1023;
  const float* W = jw == 0 ? W0 : (jw == 1 ? W1 : (jw == 2 ? W2 : W3));
  unsigned short* T = jw == 0 ? T0 : (jw == 1 ? T1 : (jw == 2 ? T2 : T3));
  __shared__ float tile[32][33];
  int k0 = (tb & 31) * 32, n0 = (tb >> 5) * 32;
  int c = t & 31, r0 = t >> 5;
#pragma unroll
  for (int i = 0; i < 4; ++i) {
    int r = r0 + i * 8;
    tile[r][c] = W[(size_t)(k0 + r) * DD + n0 + c];
  }
  __syncthreads();
#pragma unroll
  for (int i = 0; i < 4; ++i) {
    int r = r0 + i * 8;
    T[(size_t)(n0 + r) * DD + k0 + c] = f2bf(tile[c][r]);
  }
}

// ---------------------------------------------------------------------------
// Out-projection (v16): 128x128xBK32, 256 blocks, triple-buffered LDS,
// counted-vmcnt schedule. v16: removed the redundant post-stage barrier --
// the phase's exit barrier (after vmcnt) alone provides all cross-wave
// ordering: entering phase T, tile T is landed (vmcnt(4) at T-1 exit) and
// globally visible (exit barrier); stage(T+2) overwrites buf (T-1)%3 whose
// reads completed before T-1's MFMAs (compiler lgkmcnt), hence before the
// T-1 exit barrier every wave has passed. One barrier per phase.
// ---------------------------------------------------------------------------
__global__ __launch_bounds__(256, 3) void out_gemm_tri(
    const unsigned short* __restrict__ A, const unsigned short* __restrict__ BT,
    const float* __restrict__ bias, float* __restrict__ out) {
  const int i = blockIdx.x;
  const int xcd = i & 7;
  const int slot = i >> 3;            // 0..31
  const int bm = (xcd + 8 * (slot >> 3)) * 128;
  const int bn = (slot & 7) * 128;

  const int t = threadIdx.x;
  const int w = t >> 6;
  const int l = t & 63;
  const int wm = (w >> 1) * 64;
  const int wn = (w & 1) * 64;
  const int fr = l & 15;
  const int kgB = (l >> 4) * 16;        // byte offset of lane's k-group

  // [A=0/B=1][tri][128 rows x 32 k] bf16 = 48 KB
  __shared__ __align__(16) unsigned short lds[2][3][4096];

  f32x4 acc[4][4];
#pragma unroll
  for (int ii = 0; ii < 4; ++ii)
#pragma unroll
    for (int j = 0; j < 4; ++j) acc[ii][j] = (f32x4)0.f;

  // hoisted LDS read byte offsets (lane constants)
  int aoff[4], boff[4];
#pragma unroll
  for (int ii = 0; ii < 4; ++ii) {
    aoff[ii] = (wm + ii * 16 + fr) * 64 + kgB;
    boff[ii] = (wn + ii * 16 + fr) * 64 + kgB;
  }

  // hoisted staging source pointers (advance by literal k0 per tile)
  const int cc0 = w * 128 + l;
  const int cc1 = cc0 + 64;
  const int row0 = cc0 >> 2, kk0 = (cc0 & 3) * 8;
  const int row1 = cc1 >> 2, kk1 = (cc1 & 3) * 8;
  const unsigned short* a0 = A + (size_t)(bm + row0) * DD + kk0;
  const unsigned short* a1 = A + (size_t)(bm + row1) * DD + kk1;
  const unsigned short* b0 = BT + (size_t)(bn + row0) * DD + kk0;
  const unsigned short* b1 = BT + (size_t)(bn + row1) * DD + kk1;

  auto stage_tile = [&](int T) {
    if (T >= 32) return;
    const int buf = T % 3;
    const int k0 = T * 32;
    async_copy16(a0 + k0, &lds[0][buf][w * 1024]);
    async_copy16(a1 + k0, &lds[0][buf][w * 1024 + 512]);
    async_copy16(b0 + k0, &lds[1][buf][w * 1024]);
    async_copy16(b1 + k0, &lds[1][buf][w * 1024 + 512]);
  };

  auto phase = [&](int T, int vm) {
    const int buf = T % 3;
    const char* Ab = (const char*)&lds[0][buf][0];
    const char* Bb = (const char*)&lds[1][buf][0];
    bf16x8 af[4], bfr[4];
#pragma unroll
    for (int ii = 0; ii < 4; ++ii) af[ii] = *(const bf16x8*)(Ab + aoff[ii]);
#pragma unroll
    for (int j = 0; j < 4; ++j) bfr[j] = *(const bf16x8*)(Bb + boff[j]);
    stage_tile(T + 2);
    __builtin_amdgcn_s_setprio(1);
#pragma unroll
    for (int ii = 0; ii < 4; ++ii)
#pragma unroll
      for (int j = 0; j < 4; ++j)
        acc[ii][j] = __builtin_amdgcn_mfma_f32_16x16x32_bf16(af[ii], bfr[j], acc[ii][j], 0, 0, 0);
    __builtin_amdgcn_s_setprio(0);
    if (vm == 1) asm volatile("s_waitcnt vmcnt(4)" ::: "memory");
    if (vm == 2) asm volatile("s_waitcnt vmcnt(0)" ::: "memory");
    asm volatile("s_barrier" ::: "memory");
  };

  // prologue: tiles 0,1 in flight; wait tile0 landed
  stage_tile(0);
  stage_tile(1);
  asm volatile("s_waitcnt vmcnt(4)" ::: "memory");
  asm volatile("s_barrier" ::: "memory");

  for (int T = 0; T < 30; ++T) phase(T, 1);
  phase(30, 2);
  phase(31, 0);

  const int col_l = l & 15;
  const int row_l = (l >> 4) * 4;

#pragma unroll
  for (int ii = 0; ii < 4; ++ii) {
    int m_base = bm + wm + ii * 16 + row_l;
#pragma unroll
    for (int j = 0; j < 4; ++j) {
      int n = bn + wn + j * 16 + col_l;
      float bv = bias[n];
#pragma unroll
      for (int r = 0; r < 4; ++r)
        out[(size_t)(m_base + r) * DD + n] = acc[ii][j][r] + bv;
    }
  }
}

// ---------------------------------------------------------------------------
// QKV projection (v16): same one-barrier-per-phase tri template.
// ---------------------------------------------------------------------------
__global__ __launch_bounds__(256, 3) void qkv_gemm_tri(
    const unsigned short* __restrict__ A,
    const unsigned short* __restrict__ WqT, const unsigned short* __restrict__ WkT,
    const unsigned short* __restrict__ WvT,
    const float* __restrict__ bq, const float* __restrict__ bk,
    const float* __restrict__ bv,
    unsigned short* __restrict__ Qo, unsigned short* __restrict__ Ko,
    unsigned short* __restrict__ VTo) {
  const int i = blockIdx.x;
  const int xcd = i & 7;
  const int slot = i >> 3;              // 0..95
  const int bm = (xcd + 8 * (slot / 24)) * 128;   // 24 blocks share A-panel/XCD
  const int c = slot % 24;
  const int which = c >> 3;             // 0:Q 1:K 2:V
  const int bn = (c & 7) * 128;
  const unsigned short* BT = which == 0 ? WqT : (which == 1 ? WkT : WvT);
  const float* bias = which == 0 ? bq : (which == 1 ? bk : bv);

  const int t = threadIdx.x;
  const int w = t >> 6;
  const int l = t & 63;
  const int wm = (w >> 1) * 64;
  const int wn = (w & 1) * 64;
  const int fr = l & 15;
  const int kgB = (l >> 4) * 16;        // byte offset of lane's k-group

  // [A=0/B=1][tri][128 rows x 32 k] bf16 = 48 KB -> 3 blocks/CU
  __shared__ __align__(16) unsigned short lds[2][3][4096];

  f32x4 acc[4][4];
#pragma unroll
  for (int ii = 0; ii < 4; ++ii)
#pragma unroll
    for (int j = 0; j < 4; ++j) acc[ii][j] = (f32x4)0.f;

  // hoisted LDS read byte offsets (lane constants)
  int aoff[4], boff[4];
#pragma unroll
  for (int ii = 0; ii < 4; ++ii) {
    aoff[ii] = (wm + ii * 16 + fr) * 64 + kgB;
    boff[ii] = (wn + ii * 16 + fr) * 64 + kgB;
  }

  // hoisted staging source pointers (advance by literal k0 per tile)
  const int cc0 = w * 128 + l;          // (w*2+0)*64 + l
  const int cc1 = cc0 + 64;
  const int row0 = cc0 >> 2, kk0 = (cc0 & 3) * 8;
  const int row1 = cc1 >> 2, kk1 = (cc1 & 3) * 8;
  const unsigned short* a0 = A + (size_t)(bm + row0) * DD + kk0;
  const unsigned short* a1 = A + (size_t)(bm + row1) * DD + kk1;
  const unsigned short* b0 = BT + (size_t)(bn + row0) * DD + kk0;
  const unsigned short* b1 = BT + (size_t)(bn + row1) * DD + kk1;

  auto stage_tile = [&](int T) {
    if (T >= 32) return;
    const int buf = T % 3;
    const int k0 = T * 32;
    async_copy16(a0 + k0, &lds[0][buf][w * 1024]);
    async_copy16(a1 + k0, &lds[0][buf][w * 1024 + 512]);
    async_copy16(b0 + k0, &lds[1][buf][w * 1024]);
    async_copy16(b1 + k0, &lds[1][buf][w * 1024 + 512]);
  };

  auto phase = [&](int T, int vm) {
    const int buf = T % 3;
    const char* Ab = (const char*)&lds[0][buf][0];
    const char* Bb = (const char*)&lds[1][buf][0];
    bf16x8 af[4], bfr[4];
#pragma unroll
    for (int ii = 0; ii < 4; ++ii) af[ii] = *(const bf16x8*)(Ab + aoff[ii]);
#pragma unroll
    for (int j = 0; j < 4; ++j) bfr[j] = *(const bf16x8*)(Bb + boff[j]);
    stage_tile(T + 2);
    __builtin_amdgcn_s_setprio(1);
#pragma unroll
    for (int ii = 0; ii < 4; ++ii)
#pragma unroll
      for (int j = 0; j < 4; ++j)
        acc[ii][j] = __builtin_amdgcn_mfma_f32_16x16x32_bf16(af[ii], bfr[j], acc[ii][j], 0, 0, 0);
    __builtin_amdgcn_s_setprio(0);
    if (vm == 1) asm volatile("s_waitcnt vmcnt(4)" ::: "memory");
    if (vm == 2) asm volatile("s_waitcnt vmcnt(0)" ::: "memory");
    asm volatile("s_barrier" ::: "memory");
  };

  // prologue: tiles 0,1 in flight; wait tile0 landed (tile1's 4 outstanding)
  stage_tile(0);
  stage_tile(1);
  asm volatile("s_waitcnt vmcnt(4)" ::: "memory");
  asm volatile("s_barrier" ::: "memory");

  for (int T = 0; T < 30; ++T) phase(T, 1);
  phase(30, 2);    // tile31 is the only outstanding group -> drain
  phase(31, 0);

  const int col_l = l & 15;
  const int row_l = (l >> 4) * 4;
  const int b_ = bm >> 11;

  if (which != 2) {
    // Q/K: bf16 out [B,H,S,HD], scaled
    const float scl = which == 0 ? 0.18033688011112042f : 1.0f;
    unsigned short* out = which == 0 ? Qo : Ko;
#pragma unroll
    for (int ii = 0; ii < 4; ++ii) {
      int m_base = bm + wm + ii * 16 + row_l;
#pragma unroll
      for (int j = 0; j < 4; ++j) {
        int n = bn + wn + j * 16 + col_l;
        float bv = bias[n];
        int h_ = n >> 6, hd_ = n & 63;
#pragma unroll
        for (int r = 0; r < 4; ++r) {
          int m = m_base + r;
          int b2 = m >> 11, s_ = m & 2047;
          out[(((size_t)(b2 * HH + h_) * SS) + s_) * HD + hd_] =
              f2bf((acc[ii][j][r] + bv) * scl);
        }
      }
    }
  } else {
    // V: transpose 128x128 C tile via LDS, store VTo[(b*HH+h)*HD+hd][s]
    unsigned short* out = VTo;
    unsigned int* Tt = (unsigned int*)&lds[0][0][0];  // 2048 dwords scratch
    const int srow0 = bm & 2047;
#pragma unroll
    for (int p = 0; p < 4; ++p) {
      __syncthreads();
      if ((w & 1) == (p >> 1)) {
        const int jt0 = (p & 1) * 2;
#pragma unroll
        for (int jj = 0; jj < 2; ++jj) {
          int jt = jt0 + jj;
          int n_p = jj * 16 + col_l;          // n within pass [0,32)
          float bv = bias[bn + p * 32 + n_p];
#pragma unroll
          for (int ii = 0; ii < 4; ++ii) {
            int m0 = wm + ii * 16 + row_l;    // even
#pragma unroll
            for (int pr = 0; pr < 2; ++pr) {
              unsigned int val =
                  (unsigned int)f2bf(acc[ii][jt][2 * pr] + bv) |
                  ((unsigned int)f2bf(acc[ii][jt][2 * pr + 1] + bv) << 16);
              int m = m0 + 2 * pr;
              Tt[n_p * 64 + (((m >> 1)) ^ ((n_p & 7) << 2))] = val;
            }
          }
        }
      }
      __syncthreads();
#pragma unroll
      for (int cq = 0; cq < 2; ++cq) {
        int q = t + cq * 256;
        int n_p = q >> 4, cpos = q & 15;
        uint4 v = *(const uint4*)(Tt + n_p * 64 + ((cpos * 4) ^ ((n_p & 7) << 2)));
        int n_glob = bn + p * 32 + n_p;
        int h_ = n_glob >> 6, hd_ = n_glob & 63;
        *(uint4*)(out + ((size_t)((b_ * HH + h_) * HD + hd_)) * SS + srow0 + cpos * 8) = v;
      }
    }
  }
}

// ---------------------------------------------------------------------------
// MFMA flash attention v16 = v14 minus the redundant post-stage barrier
// (one full-block barrier per 64-key phase instead of two). Ordering proof
// as in out_gemm_tri header. Numerics unchanged.
// ---------------------------------------------------------------------------
__global__ __launch_bounds__(512, 2) void flash_attn_mfma(
    const unsigned short* __restrict__ Q,   // [B,H,S,HD] bf16 (pre-scaled)
    const unsigned short* __restrict__ K,   // [B,H,S,HD] bf16
    const unsigned short* __restrict__ VT,  // [B,H,HD,S] bf16
    unsigned short* __restrict__ ctx) {     // [B,S,D] bf16
  const int bh = blockIdx.x;   // FASTEST: XCD = bh % 8 -> per-XCD K/V locality
  const int qt = blockIdx.y;   // 128-row q tile
  const int b  = bh >> 4;
  const int h  = bh & 15;
  const int t  = threadIdx.x;
  const int w  = t >> 6;   // wave 0..7
  const int l  = t & 63;
  const int wg = w & 3;    // q sub-tile 0..3 (32 rows each)
  const int wh = w >> 2;   // key-subtile parity 0/1
  const int g  = l >> 4;   // lane group 0..3
  const int ln = l & 15;   // q index within 16-row tile

  const unsigned short* Qp = Q + ((size_t)bh * SS + (size_t)qt * 128 + wg * 32) * HD;
  const unsigned short* Kp = K + (size_t)bh * SS * HD;
  const unsigned short* Vp = VT + (size_t)bh * HD * SS;

  // [K=0/V=1][parity][3 bufs][4 KB tile]; K [32key][64hd], V [64hd][32key]
  __shared__ __align__(16) unsigned short smem[2][2][3][2048];
  __shared__ __align__(16) float rred[4 * 64 * 2];  // 2 KB combine scratch

  // Q as B-operand fragments: qf[nt][kb], n=ln, k = kb*32 + g*8 + j
  bf16x8 qf[2][2];
#pragma unroll
  for (int nt = 0; nt < 2; ++nt)
#pragma unroll
    for (int kb = 0; kb < 2; ++kb)
      qf[nt][kb] = *(const bf16x8*)(Qp + (nt * 16 + ln) * HD + kb * 32 + g * 8);

  f32x4 o[2][4];
#pragma unroll
  for (int nt = 0; nt < 2; ++nt)
#pragma unroll
    for (int mt = 0; mt < 4; ++mt) o[nt][mt] = (f32x4)0.f;
  float rs[2] = {0.f, 0.f};

  // ---- loop-invariant staging pointers (advance by const stride per group)
  const int sp  = w >> 2;          // parity this wave stages
  const int sq  = w & 3;           // quarter within parity tile
  const int idx = sq * 64 + l;
  const int rowK = idx >> 3;
  const int gccK = (idx & 7) ^ (rowK & 7);
  const unsigned short* kgp = Kp + (size_t)(sp * 32 + rowK) * HD + gccK * 8;
  const int rowV = idx >> 2;
  const int gc2V = (idx & 3) ^ ((rowV >> 1) & 3);
  const unsigned short* vgp = Vp + (size_t)rowV * SS + sp * 32 + gc2V * 8;
  unsigned short* dK = &smem[0][sp][0][sq * 512];   // +2048 shorts per buf
  unsigned short* dV = &smem[1][sp][0][sq * 512];

  // ---- loop-invariant ds_read byte offsets (pure lane constants)
  int ko[2][2];
#pragma unroll
  for (int kb = 0; kb < 2; ++kb)
#pragma unroll
    for (int mt = 0; mt < 2; ++mt) {
      int row = mt * 16 + ln;
      ko[kb][mt] = row * 128 + (((kb * 4 + g) ^ (row & 7)) * 16);
    }
  int vo[4];
#pragma unroll
  for (int mt = 0; mt < 4; ++mt) {
    int row = mt * 16 + ln;
    vo[mt] = row * 64 + ((g ^ ((row >> 1) & 3)) * 16);
  }
  const char* kpar = (const char*)&smem[0][wh][0][0];
  const char* vpar = (const char*)&smem[1][wh][0][0];

  // stage one 64-key group into buffer `buf`; advances source pointers
  auto stage_i = [&](int buf) {
    async_copy16(kgp, dK + buf * 2048);
    async_copy16(vgp, dV + buf * 2048);
    kgp += 64 * HD;   // next 64-key group along s
    vgp += 64;
  };

  // phase: compute group in `buf`; optionally stage into `sbuf`;
  // vm: 1 = vmcnt(2) (steady), 2 = vmcnt(0) (drain), 0 = none.
  auto phase = [&](int buf, int sbuf, bool doStage, int vm) {
    const char* Kst = kpar + buf * 4096;
    const char* Vst = vpar + buf * 4096;

    // issue all 8 ds_reads up front (buf guaranteed landed)
    bf16x8 ka[2][2], va[4];
#pragma unroll
    for (int kb = 0; kb < 2; ++kb)
#pragma unroll
      for (int mt = 0; mt < 2; ++mt)
        ka[kb][mt] = *(const bf16x8*)(Kst + ko[kb][mt]);
#pragma unroll
    for (int mt = 0; mt < 4; ++mt) va[mt] = *(const bf16x8*)(Vst + vo[mt]);

    if (doStage) stage_i(sbuf);
    __builtin_amdgcn_s_setprio(1);

    // --- S^T = K Q^T
    f32x4 st[2][2];
#pragma unroll
    for (int nt = 0; nt < 2; ++nt)
#pragma unroll
      for (int mt = 0; mt < 2; ++mt) st[nt][mt] = (f32x4)0.f;
#pragma unroll
    for (int kb = 0; kb < 2; ++kb)
#pragma unroll
      for (int mt = 0; mt < 2; ++mt) {
        st[0][mt] = __builtin_amdgcn_mfma_f32_16x16x32_bf16(ka[kb][mt], qf[0][kb], st[0][mt], 0, 0, 0);
        st[1][mt] = __builtin_amdgcn_mfma_f32_16x16x32_bf16(ka[kb][mt], qf[1][kb], st[1][mt], 0, 0, 0);
      }

    // --- p = exp2(s'); pack; permlane redistribute
    unsigned Sd[2][2][2];
#pragma unroll
    for (int nt = 0; nt < 2; ++nt) {
#pragma unroll
      for (int mt = 0; mt < 2; ++mt) {
        float p0 = fast_exp2(st[nt][mt][0]);
        float p1 = fast_exp2(st[nt][mt][1]);
        float p2 = fast_exp2(st[nt][mt][2]);
        float p3 = fast_exp2(st[nt][mt][3]);
        Sd[nt][mt][0] = __builtin_amdgcn_perm(__float_as_uint(p1), __float_as_uint(p0),
                                              0x07060302u);
        Sd[nt][mt][1] = __builtin_amdgcn_perm(__float_as_uint(p3), __float_as_uint(p2),
                                              0x07060302u);
        rs[nt] += (p0 + p1) + (p2 + p3);
      }
#pragma unroll
      for (int p = 0; p < 2; ++p) pl32_swap(Sd[nt][0][p], Sd[nt][1][p]);
#pragma unroll
      for (int p = 0; p < 2; ++p) pl16_swap(Sd[nt][0][p], Sd[nt][1][p]);
    }

    // --- O^T += V^T P^T
    bf16x8 pbv[2];
#pragma unroll
    for (int nt = 0; nt < 2; ++nt) {
      union { unsigned u[4]; bf16x8 v; } cu;
      cu.u[0] = Sd[nt][0][0];
      cu.u[1] = Sd[nt][0][1];
      cu.u[2] = Sd[nt][1][0];
      cu.u[3] = Sd[nt][1][1];
      pbv[nt] = cu.v;
    }
#pragma unroll
    for (int mt = 0; mt < 4; ++mt) {
      o[0][mt] = __builtin_amdgcn_mfma_f32_16x16x32_bf16(va[mt], pbv[0], o[0][mt], 0, 0, 0);
      o[1][mt] = __builtin_amdgcn_mfma_f32_16x16x32_bf16(va[mt], pbv[1], o[1][mt], 0, 0, 0);
    }

    __builtin_amdgcn_s_setprio(0);
    if (vm == 1) asm volatile("s_waitcnt vmcnt(2)" ::: "memory");
    if (vm == 2) asm volatile("s_waitcnt vmcnt(0)" ::: "memory");
    asm volatile("s_barrier" ::: "memory");
  };

  // prologue: groups 0,1 in flight; wait group0 landed (group1 outstanding)
  stage_i(0);
  stage_i(1);
  asm volatile("s_waitcnt vmcnt(2)" ::: "memory");
  asm volatile("s_barrier" ::: "memory");

  // 30 steady phases (bufs cycle 0,1,2; stage T+2 into (T+2)%3)
  for (int it = 0; it < 10; ++it) {
    phase(0, 2, true, 1);
    phase(1, 0, true, 1);
    phase(2, 1, true, 1);
  }
  phase(0, 0, false, 2);   // T=30: no stage; drain (group31's 2 loads)
  phase(1, 0, false, 0);   // T=31: nothing outstanding

  // --- cross-parity combine: wh=1 waves dump partial o/rs to LDS, wh=0 adds.
  __syncthreads();  // all compute done; smem reusable as scratch
  {
    float* ored = (float*)&smem[0][0][0][0];  // 4 x 64 x 32 f32 = 32 KB
    float* rb = ored + (wg * 64 + l) * 32;
    float* sb = rred + (wg * 64 + l) * 2;
    if (wh == 1) {
#pragma unroll
      for (int nt = 0; nt < 2; ++nt)
#pragma unroll
        for (int mt = 0; mt < 4; ++mt) {
          int idx2 = nt * 4 + mt;
          *(f32x4*)(rb + ((unsigned)(idx2 ^ (l & 7)) * 4)) = o[nt][mt];
        }
      sb[0] = rs[0];
      sb[1] = rs[1];
    }
    __syncthreads();
    if (wh == 1) return;
#pragma unroll
    for (int nt = 0; nt < 2; ++nt)
#pragma unroll
      for (int mt = 0; mt < 4; ++mt) {
        int idx2 = nt * 4 + mt;
        f32x4 pv = *(const f32x4*)(rb + ((unsigned)(idx2 ^ (l & 7)) * 4));
        o[nt][mt] += pv;
      }
    rs[0] += sb[0];
    rs[1] += sb[1];
  }

  // --- epilogue: reduce rs over lane groups, normalize, store bf16 ctx
#pragma unroll
  for (int nt = 0; nt < 2; ++nt) {
    float lsum = rs[nt];
    lsum += __shfl_xor(lsum, 16, 64);
    lsum += __shfl_xor(lsum, 32, 64);
    float inv = 1.f / lsum;
    int srow = qt * 128 + wg * 32 + nt * 16 + ln;
    unsigned short* cb = ctx + (size_t)(b * SS + srow) * DD + h * HD;
#pragma unroll
    for (int mt = 0; mt < 4; ++mt) {
      ushort4 u4;
      u4.x = f2bf(o[nt][mt][0] * inv);
      u4.y = f2bf(o[nt][mt][1] * inv);
      u4.z = f2bf(o[nt][mt][2] * inv);
      u4.w = f2bf(o[nt][mt][3] * inv);
      *(ushort4*)(cb + mt * 16 + 4 * g) = u4;
    }
  }
}

// ---------------------------------------------------------------------------
extern "C" void kernel_launch(void* const* d_in, const int* in_sizes, int n_in,
                              void* d_out, int out_size, void* d_ws, size_t ws_size,
                              hipStream_t stream) {
  const float* x  = (const float*)d_in[0];
  const float* Wq = (const float*)d_in[1];
  const float* bq = (const float*)d_in[2];
  const float* Wk = (const float*)d_in[3];
  const float* bk = (const float*)d_in[4];
  const float* Wv = (const float*)d_in[5];
  const float* bv = (const float*)d_in[6];
  const float* Wo = (const float*)d_in[7];
  const float* bo = (const float*)d_in[8];
  float* out = (float*)d_out;

  const size_t ELEMS = (size_t)BB * SS * DD;  // 4,194,304
  char* ws = (char*)d_ws;
  unsigned short* xb   = (unsigned short*)ws;  ws += ELEMS * 2;
  unsigned short* WqT  = (unsigned short*)ws;  ws += (size_t)DD * DD * 2;
  unsigned short* WkT  = (unsigned short*)ws;  ws += (size_t)DD * DD * 2;
  unsigned short* WvT  = (unsigned short*)ws;  ws += (size_t)DD * DD * 2;
  unsigned short* WoT  = (unsigned short*)ws;  ws += (size_t)DD * DD * 2;
  unsigned short* Qb   = (unsigned short*)ws;  ws += ELEMS * 2;
  unsigned short* Kb   = (unsigned short*)ws;  ws += ELEMS * 2;
  unsigned short* VbT  = (unsigned short*)ws;  ws += ELEMS * 2;
  unsigned short* ctxb = (unsigned short*)ws;  ws += ELEMS * 2;

  prep_kernel<<<8192, 256, 0, stream>>>(x, xb, Wq, WqT, Wk, WkT, Wv, WvT, Wo, WoT);

  qkv_gemm_tri<<<768, 256, 0, stream>>>(xb, WqT, WkT, WvT, bq, bk, bv,
                                        Qb, Kb, VbT);

  dim3 attn_grid(BB * HH, SS / 128);           // (32 bh, 16 qt) = 512 blocks
  flash_attn_mfma<<<attn_grid, 512, 0, stream>>>(Qb, Kb, VbT, ctxb);

  out_gemm_tri<<<256, 256, 0, stream>>>(ctxb, WoT, bo, out);
}

// Round 15
// 179.912 us; speedup vs baseline: 1.0265x; 1.0265x over previous
//
#include <hip/hip_runtime.h>
#include <hip/hip_bf16.h>

#define BB 2
#define SS 2048
#define DD 1024
#define HH 16
#define HD 64

typedef __attribute__((ext_vector_type(8))) short bf16x8;
typedef __attribute__((ext_vector_type(4))) float f32x4;

// round-to-nearest-even f32 -> bf16 (inputs finite)
__device__ __forceinline__ unsigned short f2bf(float f) {
  unsigned int u = __float_as_uint(f);
  return (unsigned short)((u + 0x7FFFu + ((u >> 16) & 1u)) >> 16);
}

// 2^x via hardware v_exp_f32
__device__ __forceinline__ float fast_exp2(float x) {
#if __has_builtin(__builtin_amdgcn_exp2f)
  return __builtin_amdgcn_exp2f(x);
#else
  return __expf(x * 0.6931471805599453f);
#endif
}

__device__ __forceinline__ void async_copy16(const unsigned short* gp, unsigned short* lp) {
  __builtin_amdgcn_global_load_lds(
      (const __attribute__((address_space(1))) unsigned int*)gp,
      (__attribute__((address_space(3))) unsigned int*)lp, 16, 0, 0);
}

// gfx950 cross-lane register swaps (VALU, not DS pipe).
__device__ __forceinline__ void pl32_swap(unsigned& a, unsigned& b) {
#if __has_builtin(__builtin_amdgcn_permlane32_swap)
  auto r = __builtin_amdgcn_permlane32_swap(a, b, false, false);
  a = r[0];
  b = r[1];
#else
  asm volatile("v_permlane32_swap_b32 %0, %1" : "+v"(a), "+v"(b));
#endif
}
__device__ __forceinline__ void pl16_swap(unsigned& a, unsigned& b) {
#if __has_builtin(__builtin_amdgcn_permlane16_swap)
  auto r = __builtin_amdgcn_permlane16_swap(a, b, false, false);
  a = r[0];
  b = r[1];
#else
  asm volatile("v_permlane16_swap_b32 %0, %1" : "+v"(a), "+v"(b));
#endif
}

// ---------------------------------------------------------------------------
// Fused prep: blocks [0,4096) convert x -> bf16; blocks [4096,8192) transpose
// one of the 4 weight matrices (1024 32x32 tiles each) to bf16 [N][K].
// ---------------------------------------------------------------------------
__global__ __launch_bounds__(256) void prep_kernel(
    const float* __restrict__ x, unsigned short* __restrict__ xb,
    const float* __restrict__ W0, unsigned short* __restrict__ T0,
    const float* __restrict__ W1, unsigned short* __restrict__ T1,
    const float* __restrict__ W2, unsigned short* __restrict__ T2,
    const float* __restrict__ W3, unsigned short* __restrict__ T3) {
  const int blk = blockIdx.x;
  const int t = threadIdx.x;
  if (blk < 4096) {
    int i = blk * 1024 + t * 4;
    float4 v = *(const float4*)(x + i);
    ushort4 u;
    u.x = f2bf(v.x); u.y = f2bf(v.y); u.z = f2bf(v.z); u.w = f2bf(v.w);
    *(ushort4*)(xb + i) = u;
    return;
  }
  const int j = blk - 4096;
  const int jw = j >> 10;          // which weight
  const int tb = j & 1023;
  const float* W = jw == 0 ? W0 : (jw == 1 ? W1 : (jw == 2 ? W2 : W3));
  unsigned short* T = jw == 0 ? T0 : (jw == 1 ? T1 : (jw == 2 ? T2 : T3));
  __shared__ float tile[32][33];
  int k0 = (tb & 31) * 32, n0 = (tb >> 5) * 32;
  int c = t & 31, r0 = t >> 5;
#pragma unroll
  for (int i = 0; i < 4; ++i) {
    int r = r0 + i * 8;
    tile[r][c] = W[(size_t)(k0 + r) * DD + n0 + c];
  }
  __syncthreads();
#pragma unroll
  for (int i = 0; i < 4; ++i) {
    int r = r0 + i * 8;
    T[(size_t)(n0 + r) * DD + k0 + c] = f2bf(tile[c][r]);
  }
}

// ---------------------------------------------------------------------------
// Out-projection (v15, R12-verified): 128x128xBK32, 256 blocks, triple-
// buffered LDS, counted-vmcnt schedule with BOTH barriers per phase.
// NOTE (v16 post-mortem): the post-stage barrier is schedule-load-bearing --
// it pins the global_load_lds issue BEFORE the MFMA cluster; removing it
// let the scheduler sink the prefetch and cost ~2.5us on flash. Keep it.
// ---------------------------------------------------------------------------
__global__ __launch_bounds__(256, 3) void out_gemm_tri(
    const unsigned short* __restrict__ A, const unsigned short* __restrict__ BT,
    const float* __restrict__ bias, float* __restrict__ out) {
  const int i = blockIdx.x;
  const int xcd = i & 7;
  const int slot = i >> 3;            // 0..31
  const int bm = (xcd + 8 * (slot >> 3)) * 128;
  const int bn = (slot & 7) * 128;

  const int t = threadIdx.x;
  const int w = t >> 6;
  const int l = t & 63;
  const int wm = (w >> 1) * 64;
  const int wn = (w & 1) * 64;
  const int fr = l & 15;
  const int kgB = (l >> 4) * 16;        // byte offset of lane's k-group

  // [A=0/B=1][tri][128 rows x 32 k] bf16 = 48 KB
  __shared__ __align__(16) unsigned short lds[2][3][4096];

  f32x4 acc[4][4];
#pragma unroll
  for (int ii = 0; ii < 4; ++ii)
#pragma unroll
    for (int j = 0; j < 4; ++j) acc[ii][j] = (f32x4)0.f;

  // hoisted LDS read byte offsets (lane constants)
  int aoff[4], boff[4];
#pragma unroll
  for (int ii = 0; ii < 4; ++ii) {
    aoff[ii] = (wm + ii * 16 + fr) * 64 + kgB;
    boff[ii] = (wn + ii * 16 + fr) * 64 + kgB;
  }

  // hoisted staging source pointers (advance by literal k0 per tile)
  const int cc0 = w * 128 + l;
  const int cc1 = cc0 + 64;
  const int row0 = cc0 >> 2, kk0 = (cc0 & 3) * 8;
  const int row1 = cc1 >> 2, kk1 = (cc1 & 3) * 8;
  const unsigned short* a0 = A + (size_t)(bm + row0) * DD + kk0;
  const unsigned short* a1 = A + (size_t)(bm + row1) * DD + kk1;
  const unsigned short* b0 = BT + (size_t)(bn + row0) * DD + kk0;
  const unsigned short* b1 = BT + (size_t)(bn + row1) * DD + kk1;

  auto stage_tile = [&](int T) {
    if (T >= 32) return;
    const int buf = T % 3;
    const int k0 = T * 32;
    async_copy16(a0 + k0, &lds[0][buf][w * 1024]);
    async_copy16(a1 + k0, &lds[0][buf][w * 1024 + 512]);
    async_copy16(b0 + k0, &lds[1][buf][w * 1024]);
    async_copy16(b1 + k0, &lds[1][buf][w * 1024 + 512]);
  };

  auto phase = [&](int T, int vm) {
    const int buf = T % 3;
    const char* Ab = (const char*)&lds[0][buf][0];
    const char* Bb = (const char*)&lds[1][buf][0];
    bf16x8 af[4], bfr[4];
#pragma unroll
    for (int ii = 0; ii < 4; ++ii) af[ii] = *(const bf16x8*)(Ab + aoff[ii]);
#pragma unroll
    for (int j = 0; j < 4; ++j) bfr[j] = *(const bf16x8*)(Bb + boff[j]);
    stage_tile(T + 2);
    asm volatile("s_barrier" ::: "memory");
    __builtin_amdgcn_s_setprio(1);
#pragma unroll
    for (int ii = 0; ii < 4; ++ii)
#pragma unroll
      for (int j = 0; j < 4; ++j)
        acc[ii][j] = __builtin_amdgcn_mfma_f32_16x16x32_bf16(af[ii], bfr[j], acc[ii][j], 0, 0, 0);
    __builtin_amdgcn_s_setprio(0);
    if (vm == 1) asm volatile("s_waitcnt vmcnt(4)" ::: "memory");
    if (vm == 2) asm volatile("s_waitcnt vmcnt(0)" ::: "memory");
    asm volatile("s_barrier" ::: "memory");
  };

  // prologue: tiles 0,1 in flight; wait tile0 landed
  stage_tile(0);
  stage_tile(1);
  asm volatile("s_waitcnt vmcnt(4)" ::: "memory");
  asm volatile("s_barrier" ::: "memory");

  for (int T = 0; T < 30; ++T) phase(T, 1);
  phase(30, 2);
  phase(31, 0);

  const int col_l = l & 15;
  const int row_l = (l >> 4) * 4;

#pragma unroll
  for (int ii = 0; ii < 4; ++ii) {
    int m_base = bm + wm + ii * 16 + row_l;
#pragma unroll
    for (int j = 0; j < 4; ++j) {
      int n = bn + wn + j * 16 + col_l;
      float bv = bias[n];
#pragma unroll
      for (int r = 0; r < 4; ++r)
        out[(size_t)(m_base + r) * DD + n] = acc[ii][j][r] + bv;
    }
  }
}

// ---------------------------------------------------------------------------
// QKV projection (R9/R12-verified): 128x128xBK32, 768 blocks, triple-
// buffered LDS, counted-vmcnt raw-asm schedule, setprio, BOTH barriers.
// ---------------------------------------------------------------------------
__global__ __launch_bounds__(256, 3) void qkv_gemm_tri(
    const unsigned short* __restrict__ A,
    const unsigned short* __restrict__ WqT, const unsigned short* __restrict__ WkT,
    const unsigned short* __restrict__ WvT,
    const float* __restrict__ bq, const float* __restrict__ bk,
    const float* __restrict__ bv,
    unsigned short* __restrict__ Qo, unsigned short* __restrict__ Ko,
    unsigned short* __restrict__ VTo) {
  const int i = blockIdx.x;
  const int xcd = i & 7;
  const int slot = i >> 3;              // 0..95
  const int bm = (xcd + 8 * (slot / 24)) * 128;   // 24 blocks share A-panel/XCD
  const int c = slot % 24;
  const int which = c >> 3;             // 0:Q 1:K 2:V
  const int bn = (c & 7) * 128;
  const unsigned short* BT = which == 0 ? WqT : (which == 1 ? WkT : WvT);
  const float* bias = which == 0 ? bq : (which == 1 ? bk : bv);

  const int t = threadIdx.x;
  const int w = t >> 6;
  const int l = t & 63;
  const int wm = (w >> 1) * 64;
  const int wn = (w & 1) * 64;
  const int fr = l & 15;
  const int kgB = (l >> 4) * 16;        // byte offset of lane's k-group

  // [A=0/B=1][tri][128 rows x 32 k] bf16 = 48 KB -> 3 blocks/CU
  __shared__ __align__(16) unsigned short lds[2][3][4096];

  f32x4 acc[4][4];
#pragma unroll
  for (int ii = 0; ii < 4; ++ii)
#pragma unroll
    for (int j = 0; j < 4; ++j) acc[ii][j] = (f32x4)0.f;

  // hoisted LDS read byte offsets (lane constants)
  int aoff[4], boff[4];
#pragma unroll
  for (int ii = 0; ii < 4; ++ii) {
    aoff[ii] = (wm + ii * 16 + fr) * 64 + kgB;
    boff[ii] = (wn + ii * 16 + fr) * 64 + kgB;
  }

  // hoisted staging source pointers (advance by literal k0 per tile)
  const int cc0 = w * 128 + l;          // (w*2+0)*64 + l
  const int cc1 = cc0 + 64;
  const int row0 = cc0 >> 2, kk0 = (cc0 & 3) * 8;
  const int row1 = cc1 >> 2, kk1 = (cc1 & 3) * 8;
  const unsigned short* a0 = A + (size_t)(bm + row0) * DD + kk0;
  const unsigned short* a1 = A + (size_t)(bm + row1) * DD + kk1;
  const unsigned short* b0 = BT + (size_t)(bn + row0) * DD + kk0;
  const unsigned short* b1 = BT + (size_t)(bn + row1) * DD + kk1;

  auto stage_tile = [&](int T) {
    if (T >= 32) return;
    const int buf = T % 3;
    const int k0 = T * 32;
    async_copy16(a0 + k0, &lds[0][buf][w * 1024]);
    async_copy16(a1 + k0, &lds[0][buf][w * 1024 + 512]);
    async_copy16(b0 + k0, &lds[1][buf][w * 1024]);
    async_copy16(b1 + k0, &lds[1][buf][w * 1024 + 512]);
  };

  auto phase = [&](int T, int vm) {
    const int buf = T % 3;
    const char* Ab = (const char*)&lds[0][buf][0];
    const char* Bb = (const char*)&lds[1][buf][0];
    bf16x8 af[4], bfr[4];
#pragma unroll
    for (int ii = 0; ii < 4; ++ii) af[ii] = *(const bf16x8*)(Ab + aoff[ii]);
#pragma unroll
    for (int j = 0; j < 4; ++j) bfr[j] = *(const bf16x8*)(Bb + boff[j]);
    stage_tile(T + 2);
    asm volatile("s_barrier" ::: "memory");
    __builtin_amdgcn_s_setprio(1);
#pragma unroll
    for (int ii = 0; ii < 4; ++ii)
#pragma unroll
      for (int j = 0; j < 4; ++j)
        acc[ii][j] = __builtin_amdgcn_mfma_f32_16x16x32_bf16(af[ii], bfr[j], acc[ii][j], 0, 0, 0);
    __builtin_amdgcn_s_setprio(0);
    if (vm == 1) asm volatile("s_waitcnt vmcnt(4)" ::: "memory");
    if (vm == 2) asm volatile("s_waitcnt vmcnt(0)" ::: "memory");
    asm volatile("s_barrier" ::: "memory");
  };

  // prologue: tiles 0,1 in flight; wait tile0 landed (tile1's 4 outstanding)
  stage_tile(0);
  stage_tile(1);
  asm volatile("s_waitcnt vmcnt(4)" ::: "memory");
  asm volatile("s_barrier" ::: "memory");

  for (int T = 0; T < 30; ++T) phase(T, 1);
  phase(30, 2);    // tile31 is the only outstanding group -> drain
  phase(31, 0);

  const int col_l = l & 15;
  const int row_l = (l >> 4) * 4;
  const int b_ = bm >> 11;

  if (which != 2) {
    // Q/K: bf16 out [B,H,S,HD], scaled
    const float scl = which == 0 ? 0.18033688011112042f : 1.0f;
    unsigned short* out = which == 0 ? Qo : Ko;
#pragma unroll
    for (int ii = 0; ii < 4; ++ii) {
      int m_base = bm + wm + ii * 16 + row_l;
#pragma unroll
      for (int j = 0; j < 4; ++j) {
        int n = bn + wn + j * 16 + col_l;
        float bv = bias[n];
        int h_ = n >> 6, hd_ = n & 63;
#pragma unroll
        for (int r = 0; r < 4; ++r) {
          int m = m_base + r;
          int b2 = m >> 11, s_ = m & 2047;
          out[(((size_t)(b2 * HH + h_) * SS) + s_) * HD + hd_] =
              f2bf((acc[ii][j][r] + bv) * scl);
        }
      }
    }
  } else {
    // V: transpose 128x128 C tile via LDS, store VTo[(b*HH+h)*HD+hd][s]
    unsigned short* out = VTo;
    unsigned int* Tt = (unsigned int*)&lds[0][0][0];  // 2048 dwords scratch
    const int srow0 = bm & 2047;
#pragma unroll
    for (int p = 0; p < 4; ++p) {
      __syncthreads();
      if ((w & 1) == (p >> 1)) {
        const int jt0 = (p & 1) * 2;
#pragma unroll
        for (int jj = 0; jj < 2; ++jj) {
          int jt = jt0 + jj;
          int n_p = jj * 16 + col_l;          // n within pass [0,32)
          float bv = bias[bn + p * 32 + n_p];
#pragma unroll
          for (int ii = 0; ii < 4; ++ii) {
            int m0 = wm + ii * 16 + row_l;    // even
#pragma unroll
            for (int pr = 0; pr < 2; ++pr) {
              unsigned int val =
                  (unsigned int)f2bf(acc[ii][jt][2 * pr] + bv) |
                  ((unsigned int)f2bf(acc[ii][jt][2 * pr + 1] + bv) << 16);
              int m = m0 + 2 * pr;
              Tt[n_p * 64 + (((m >> 1)) ^ ((n_p & 7) << 2))] = val;
            }
          }
        }
      }
      __syncthreads();
#pragma unroll
      for (int cq = 0; cq < 2; ++cq) {
        int q = t + cq * 256;
        int n_p = q >> 4, cpos = q & 15;
        uint4 v = *(const uint4*)(Tt + n_p * 64 + ((cpos * 4) ^ ((n_p & 7) << 2)));
        int n_glob = bn + p * 32 + n_p;
        int h_ = n_glob >> 6, hd_ = n_glob & 63;
        *(uint4*)(out + ((size_t)((b_ * HH + h_) * HD + hd_)) * SS + srow0 + cpos * 8) = v;
      }
    }
  }
}

// ---------------------------------------------------------------------------
// MFMA flash attention v14 (R11/R12-verified best: 43.5-44.1 us): 32 q-rows/
// wave, 32-key parity subtiles, tri-buffered staging with counted vmcnt(2)
// (never drain-0 in loop), raw s_barrier pair per phase, setprio, hoisted
// addressing, bh-fastest grid, permlane P redistribution.
// ---------------------------------------------------------------------------
__global__ __launch_bounds__(512, 2) void flash_attn_mfma(
    const unsigned short* __restrict__ Q,   // [B,H,S,HD] bf16 (pre-scaled)
    const unsigned short* __restrict__ K,   // [B,H,S,HD] bf16
    const unsigned short* __restrict__ VT,  // [B,H,HD,S] bf16
    unsigned short* __restrict__ ctx) {     // [B,S,D] bf16
  const int bh = blockIdx.x;   // FASTEST: XCD = bh % 8 -> per-XCD K/V locality
  const int qt = blockIdx.y;   // 128-row q tile
  const int b  = bh >> 4;
  const int h  = bh & 15;
  const int t  = threadIdx.x;
  const int w  = t >> 6;   // wave 0..7
  const int l  = t & 63;
  const int wg = w & 3;    // q sub-tile 0..3 (32 rows each)
  const int wh = w >> 2;   // key-subtile parity 0/1
  const int g  = l >> 4;   // lane group 0..3
  const int ln = l & 15;   // q index within 16-row tile

  const unsigned short* Qp = Q + ((size_t)bh * SS + (size_t)qt * 128 + wg * 32) * HD;
  const unsigned short* Kp = K + (size_t)bh * SS * HD;
  const unsigned short* Vp = VT + (size_t)bh * HD * SS;

  // [K=0/V=1][parity][3 bufs][4 KB tile]; K [32key][64hd], V [64hd][32key]
  __shared__ __align__(16) unsigned short smem[2][2][3][2048];
  __shared__ __align__(16) float rred[4 * 64 * 2];  // 2 KB combine scratch

  // Q as B-operand fragments: qf[nt][kb], n=ln, k = kb*32 + g*8 + j
  bf16x8 qf[2][2];
#pragma unroll
  for (int nt = 0; nt < 2; ++nt)
#pragma unroll
    for (int kb = 0; kb < 2; ++kb)
      qf[nt][kb] = *(const bf16x8*)(Qp + (nt * 16 + ln) * HD + kb * 32 + g * 8);

  f32x4 o[2][4];
#pragma unroll
  for (int nt = 0; nt < 2; ++nt)
#pragma unroll
    for (int mt = 0; mt < 4; ++mt) o[nt][mt] = (f32x4)0.f;
  float rs[2] = {0.f, 0.f};

  // ---- loop-invariant staging pointers (advance by const stride per group)
  const int sp  = w >> 2;          // parity this wave stages
  const int sq  = w & 3;           // quarter within parity tile
  const int idx = sq * 64 + l;
  const int rowK = idx >> 3;
  const int gccK = (idx & 7) ^ (rowK & 7);
  const unsigned short* kgp = Kp + (size_t)(sp * 32 + rowK) * HD + gccK * 8;
  const int rowV = idx >> 2;
  const int gc2V = (idx & 3) ^ ((rowV >> 1) & 3);
  const unsigned short* vgp = Vp + (size_t)rowV * SS + sp * 32 + gc2V * 8;
  unsigned short* dK = &smem[0][sp][0][sq * 512];   // +2048 shorts per buf
  unsigned short* dV = &smem[1][sp][0][sq * 512];

  // ---- loop-invariant ds_read byte offsets (pure lane constants)
  int ko[2][2];
#pragma unroll
  for (int kb = 0; kb < 2; ++kb)
#pragma unroll
    for (int mt = 0; mt < 2; ++mt) {
      int row = mt * 16 + ln;
      ko[kb][mt] = row * 128 + (((kb * 4 + g) ^ (row & 7)) * 16);
    }
  int vo[4];
#pragma unroll
  for (int mt = 0; mt < 4; ++mt) {
    int row = mt * 16 + ln;
    vo[mt] = row * 64 + ((g ^ ((row >> 1) & 3)) * 16);
  }
  const char* kpar = (const char*)&smem[0][wh][0][0];
  const char* vpar = (const char*)&smem[1][wh][0][0];

  // stage one 64-key group into buffer `buf`; advances source pointers
  auto stage_i = [&](int buf) {
    async_copy16(kgp, dK + buf * 2048);
    async_copy16(vgp, dV + buf * 2048);
    kgp += 64 * HD;   // next 64-key group along s
    vgp += 64;
  };

  // phase: compute group in `buf`; optionally stage into `sbuf`;
  // vm: 1 = vmcnt(2) (steady), 2 = vmcnt(0) (drain), 0 = none.
  auto phase = [&](int buf, int sbuf, bool doStage, int vm) {
    const char* Kst = kpar + buf * 4096;
    const char* Vst = vpar + buf * 4096;

    // issue all 8 ds_reads up front (buf guaranteed landed)
    bf16x8 ka[2][2], va[4];
#pragma unroll
    for (int kb = 0; kb < 2; ++kb)
#pragma unroll
      for (int mt = 0; mt < 2; ++mt)
        ka[kb][mt] = *(const bf16x8*)(Kst + ko[kb][mt]);
#pragma unroll
    for (int mt = 0; mt < 4; ++mt) va[mt] = *(const bf16x8*)(Vst + vo[mt]);

    if (doStage) stage_i(sbuf);
    asm volatile("s_barrier" ::: "memory");
    __builtin_amdgcn_s_setprio(1);

    // --- S^T = K Q^T
    f32x4 st[2][2];
#pragma unroll
    for (int nt = 0; nt < 2; ++nt)
#pragma unroll
      for (int mt = 0; mt < 2; ++mt) st[nt][mt] = (f32x4)0.f;
#pragma unroll
    for (int kb = 0; kb < 2; ++kb)
#pragma unroll
      for (int mt = 0; mt < 2; ++mt) {
        st[0][mt] = __builtin_amdgcn_mfma_f32_16x16x32_bf16(ka[kb][mt], qf[0][kb], st[0][mt], 0, 0, 0);
        st[1][mt] = __builtin_amdgcn_mfma_f32_16x16x32_bf16(ka[kb][mt], qf[1][kb], st[1][mt], 0, 0, 0);
      }

    // --- p = exp2(s'); pack; permlane redistribute
    unsigned Sd[2][2][2];
#pragma unroll
    for (int nt = 0; nt < 2; ++nt) {
#pragma unroll
      for (int mt = 0; mt < 2; ++mt) {
        float p0 = fast_exp2(st[nt][mt][0]);
        float p1 = fast_exp2(st[nt][mt][1]);
        float p2 = fast_exp2(st[nt][mt][2]);
        float p3 = fast_exp2(st[nt][mt][3]);
        Sd[nt][mt][0] = __builtin_amdgcn_perm(__float_as_uint(p1), __float_as_uint(p0),
                                              0x07060302u);
        Sd[nt][mt][1] = __builtin_amdgcn_perm(__float_as_uint(p3), __float_as_uint(p2),
                                              0x07060302u);
        rs[nt] += (p0 + p1) + (p2 + p3);
      }
#pragma unroll
      for (int p = 0; p < 2; ++p) pl32_swap(Sd[nt][0][p], Sd[nt][1][p]);
#pragma unroll
      for (int p = 0; p < 2; ++p) pl16_swap(Sd[nt][0][p], Sd[nt][1][p]);
    }

    // --- O^T += V^T P^T
    bf16x8 pbv[2];
#pragma unroll
    for (int nt = 0; nt < 2; ++nt) {
      union { unsigned u[4]; bf16x8 v; } cu;
      cu.u[0] = Sd[nt][0][0];
      cu.u[1] = Sd[nt][0][1];
      cu.u[2] = Sd[nt][1][0];
      cu.u[3] = Sd[nt][1][1];
      pbv[nt] = cu.v;
    }
#pragma unroll
    for (int mt = 0; mt < 4; ++mt) {
      o[0][mt] = __builtin_amdgcn_mfma_f32_16x16x32_bf16(va[mt], pbv[0], o[0][mt], 0, 0, 0);
      o[1][mt] = __builtin_amdgcn_mfma_f32_16x16x32_bf16(va[mt], pbv[1], o[1][mt], 0, 0, 0);
    }

    __builtin_amdgcn_s_setprio(0);
    if (vm == 1) asm volatile("s_waitcnt vmcnt(2)" ::: "memory");
    if (vm == 2) asm volatile("s_waitcnt vmcnt(0)" ::: "memory");
    asm volatile("s_barrier" ::: "memory");
  };

  // prologue: groups 0,1 in flight; wait group0 landed (group1 outstanding)
  stage_i(0);
  stage_i(1);
  asm volatile("s_waitcnt vmcnt(2)" ::: "memory");
  asm volatile("s_barrier" ::: "memory");

  // 30 steady phases (bufs cycle 0,1,2; stage T+2 into (T+2)%3)
  for (int it = 0; it < 10; ++it) {
    phase(0, 2, true, 1);
    phase(1, 0, true, 1);
    phase(2, 1, true, 1);
  }
  phase(0, 0, false, 2);   // T=30: no stage; drain (group31's 2 loads)
  phase(1, 0, false, 0);   // T=31: nothing outstanding

  // --- cross-parity combine: wh=1 waves dump partial o/rs to LDS, wh=0 adds.
  __syncthreads();  // all compute done; smem reusable as scratch
  {
    float* ored = (float*)&smem[0][0][0][0];  // 4 x 64 x 32 f32 = 32 KB
    float* rb = ored + (wg * 64 + l) * 32;
    float* sb = rred + (wg * 64 + l) * 2;
    if (wh == 1) {
#pragma unroll
      for (int nt = 0; nt < 2; ++nt)
#pragma unroll
        for (int mt = 0; mt < 4; ++mt) {
          int idx2 = nt * 4 + mt;
          *(f32x4*)(rb + ((unsigned)(idx2 ^ (l & 7)) * 4)) = o[nt][mt];
        }
      sb[0] = rs[0];
      sb[1] = rs[1];
    }
    __syncthreads();
    if (wh == 1) return;
#pragma unroll
    for (int nt = 0; nt < 2; ++nt)
#pragma unroll
      for (int mt = 0; mt < 4; ++mt) {
        int idx2 = nt * 4 + mt;
        f32x4 pv = *(const f32x4*)(rb + ((unsigned)(idx2 ^ (l & 7)) * 4));
        o[nt][mt] += pv;
      }
    rs[0] += sb[0];
    rs[1] += sb[1];
  }

  // --- epilogue: reduce rs over lane groups, normalize, store bf16 ctx
#pragma unroll
  for (int nt = 0; nt < 2; ++nt) {
    float lsum = rs[nt];
    lsum += __shfl_xor(lsum, 16, 64);
    lsum += __shfl_xor(lsum, 32, 64);
    float inv = 1.f / lsum;
    int srow = qt * 128 + wg * 32 + nt * 16 + ln;
    unsigned short* cb = ctx + (size_t)(b * SS + srow) * DD + h * HD;
#pragma unroll
    for (int mt = 0; mt < 4; ++mt) {
      ushort4 u4;
      u4.x = f2bf(o[nt][mt][0] * inv);
      u4.y = f2bf(o[nt][mt][1] * inv);
      u4.z = f2bf(o[nt][mt][2] * inv);
      u4.w = f2bf(o[nt][mt][3] * inv);
      *(ushort4*)(cb + mt * 16 + 4 * g) = u4;
    }
  }
}

// ---------------------------------------------------------------------------
extern "C" void kernel_launch(void* const* d_in, const int* in_sizes, int n_in,
                              void* d_out, int out_size, void* d_ws, size_t ws_size,
                              hipStream_t stream) {
  const float* x  = (const float*)d_in[0];
  const float* Wq = (const float*)d_in[1];
  const float* bq = (const float*)d_in[2];
  const float* Wk = (const float*)d_in[3];
  const float* bk = (const float*)d_in[4];
  const float* Wv = (const float*)d_in[5];
  const float* bv = (const float*)d_in[6];
  const float* Wo = (const float*)d_in[7];
  const float* bo = (const float*)d_in[8];
  float* out = (float*)d_out;

  const size_t ELEMS = (size_t)BB * SS * DD;  // 4,194,304
  char* ws = (char*)d_ws;
  unsigned short* xb   = (unsigned short*)ws;  ws += ELEMS * 2;
  unsigned short* WqT  = (unsigned short*)ws;  ws += (size_t)DD * DD * 2;
  unsigned short* WkT  = (unsigned short*)ws;  ws += (size_t)DD * DD * 2;
  unsigned short* WvT  = (unsigned short*)ws;  ws += (size_t)DD * DD * 2;
  unsigned short* WoT  = (unsigned short*)ws;  ws += (size_t)DD * DD * 2;
  unsigned short* Qb   = (unsigned short*)ws;  ws += ELEMS * 2;
  unsigned short* Kb   = (unsigned short*)ws;  ws += ELEMS * 2;
  unsigned short* VbT  = (unsigned short*)ws;  ws += ELEMS * 2;
  unsigned short* ctxb = (unsigned short*)ws;  ws += ELEMS * 2;

  prep_kernel<<<8192, 256, 0, stream>>>(x, xb, Wq, WqT, Wk, WkT, Wv, WvT, Wo, WoT);

  qkv_gemm_tri<<<768, 256, 0, stream>>>(xb, WqT, WkT, WvT, bq, bk, bv,
                                        Qb, Kb, VbT);

  dim3 attn_grid(BB * HH, SS / 128);           // (32 bh, 16 qt) = 512 blocks
  flash_attn_mfma<<<attn_grid, 512, 0, stream>>>(Qb, Kb, VbT, ctxb);

  out_gemm_tri<<<256, 256, 0, stream>>>(ctxb, WoT, bo, out);
}